// Round 11
// baseline (2037.140 us; speedup 1.0000x reference)
//
#include <hip/hip_runtime.h>

#define NB 8
#define NN 4096
#define MM 4096
#define CC 256
#define NPART 128   /* fused partial slots per batch */

typedef unsigned short u16;
typedef __attribute__((ext_vector_type(4))) unsigned short u16x4;
typedef __attribute__((ext_vector_type(8))) short s16x8;
typedef __attribute__((ext_vector_type(4))) float f32x4;

#define INV_EPS 33.333333333333336f
#define EXP2_SCALE 48.089834696296504f   /* INV_EPS / ln(2) */
#define POWER   0.94339622641509435f     /* 0.5/(0.5+0.03) */
#define PROB    (1.0f/4096.0f)

static __device__ __forceinline__ float bf2f(u16 h) {
    union { unsigned int u; float f; } v;
    v.u = ((unsigned int)h) << 16;
    return v.f;
}
static __device__ __forceinline__ u16 f2bf(float f) {
    union { float f; unsigned int u; } v;
    v.f = f;
    unsigned int u = v.u;
    u += 0x7fffu + ((u >> 16) & 1u);   // round-to-nearest-even
    return (u16)(u >> 16);
}
static __device__ __forceinline__ float gfun(float x) {
    // (PROB / (x + 1e-8))^POWER, x > 0
    return exp2f(POWER * log2f(PROB / (x + 1e-8f)));
}

// ---------------------------------------------------------------------------
// L2-normalize rows of (rows x 256) fp32 -> bf16. One wave per row.
// ---------------------------------------------------------------------------
__global__ __launch_bounds__(256) void norm_kernel(const float* __restrict__ src,
                                                   u16* __restrict__ dst)
{
    const int t = threadIdx.x, w = t >> 6, lane = t & 63;
    const size_t row = (size_t)blockIdx.x * 4 + w;
    const float* sp = src + row * CC + lane * 4;
    f32x4 v = *(const f32x4*)sp;
    float s = v.x * v.x + v.y * v.y + v.z * v.z + v.w * v.w;
    for (int o = 32; o > 0; o >>= 1) s += __shfl_xor(s, o);
    float rn = rsqrtf(s + 1e-8f);
    u16x4 o4;
    o4.x = f2bf(v.x * rn); o4.y = f2bf(v.y * rn);
    o4.z = f2bf(v.z * rn); o4.w = f2bf(v.w * rn);
    *(u16x4*)(dst + row * CC + lane * 4) = o4;
}

// ---------------------------------------------------------------------------
// Strip GEMM: Ks[ls][r][c] = exp((f1s[ls][r]·f2s[ls][c] - 1)/eps), bf16 out.
// Epilogue writes iteration-1 colsum partial (slot = by, plain stores, no
// atomics). LDSS=68: fragment-read bank = 2*l15+4*quad mod 32 -> <=2-way.
// launch_bounds (256,3): conflict-free LDS + 3 blocks/CU.
// ---------------------------------------------------------------------------
#define LDSS 68   /* 64 + 4 pad, in u16 units: conflict-free MFMA reads */

__global__ __launch_bounds__(256, 3) void gemm_exp_kernel(
    const u16* __restrict__ f1s, const u16* __restrict__ f2s,
    u16* __restrict__ Ks, float* __restrict__ part)
{
    const int t = threadIdx.x;
    const int w = t >> 6, lane = t & 63;
    const int quad = lane >> 4, l15 = lane & 15;
    const int bx = blockIdx.x;   // c-tile (f2 rows)
    const int by = blockIdx.y;   // r-tile (f1 rows)
    const int ls = blockIdx.z;   // local batch in strip

    __shared__ u16 As[128 * LDSS];
    __shared__ u16 Bs[128 * LDSS];
    __shared__ float csum4[4][64];   // per-wave colsum partials (no atomics)

    csum4[w][lane] = 0.f;   // covered by first loop's __syncthreads

    const u16* f2base = f2s + ((size_t)ls * MM + (size_t)bx * 128) * CC;
    const u16* f1base = f1s + ((size_t)ls * NN + (size_t)by * 128) * CC;

    f32x4 acc[4][4];
#pragma unroll
    for (int i = 0; i < 4; ++i)
#pragma unroll
        for (int j = 0; j < 4; ++j) acc[i][j] = (f32x4){0.f, 0.f, 0.f, 0.f};

    const int g_r = t >> 3;
    const int g_c = (t & 7) << 3;

    for (int kt = 0; kt < 4; ++kt) {
        const int k0 = kt * 64;
        __syncthreads();
#pragma unroll
        for (int i = 0; i < 4; ++i) {
            const int row = g_r + i * 32;
            s16x8 va = *(const s16x8*)(f2base + (size_t)row * CC + k0 + g_c);
            s16x8 vb = *(const s16x8*)(f1base + (size_t)row * CC + k0 + g_c);
            *(s16x8*)&As[row * LDSS + g_c] = va;
            *(s16x8*)&Bs[row * LDSS + g_c] = vb;
        }
        __syncthreads();
#pragma unroll
        for (int s = 0; s < 2; ++s) {
            s16x8 af[4], bfr[4];
#pragma unroll
            for (int i = 0; i < 4; ++i)
                af[i] = *(const s16x8*)&As[((w & 1) * 64 + i * 16 + l15) * LDSS + s * 32 + quad * 8];
#pragma unroll
            for (int j = 0; j < 4; ++j)
                bfr[j] = *(const s16x8*)&Bs[((w >> 1) * 64 + j * 16 + l15) * LDSS + s * 32 + quad * 8];
#pragma unroll
            for (int i = 0; i < 4; ++i)
#pragma unroll
                for (int j = 0; j < 4; ++j)
                    acc[i][j] = __builtin_amdgcn_mfma_f32_16x16x32_bf16(af[i], bfr[j], acc[i][j], 0, 0, 0);
        }
    }

    u16* kb = Ks + (size_t)ls * NN * MM;
    const int rbase = by * 128 + (w >> 1) * 64 + l15;
    const int cbase = bx * 128 + (w & 1) * 64 + quad * 4;
    float partl[4][4];
#pragma unroll
    for (int i = 0; i < 4; ++i)
#pragma unroll
        for (int e = 0; e < 4; ++e) partl[i][e] = 0.f;

#pragma unroll
    for (int j = 0; j < 4; ++j) {
        const int r = rbase + j * 16;
#pragma unroll
        for (int i = 0; i < 4; ++i) {
            const int c = cbase + i * 16;
            f32x4 v = acc[i][j];
            const float e0 = exp2f((v.x - 1.f) * EXP2_SCALE);
            const float e1 = exp2f((v.y - 1.f) * EXP2_SCALE);
            const float e2 = exp2f((v.z - 1.f) * EXP2_SCALE);
            const float e3 = exp2f((v.w - 1.f) * EXP2_SCALE);
            u16x4 o;
            o.x = f2bf(e0); o.y = f2bf(e1); o.z = f2bf(e2); o.w = f2bf(e3);
            *(u16x4*)&kb[(size_t)r * MM + c] = o;
            partl[i][0] += e0; partl[i][1] += e1; partl[i][2] += e2; partl[i][3] += e3;
        }
    }

    // reduce colsums over the 16 l15 lanes of each quad; plain += into the
    // wave-private region (active lanes hit distinct addresses -> no race)
#pragma unroll
    for (int i = 0; i < 4; ++i)
#pragma unroll
        for (int e = 0; e < 4; ++e) {
            float v = partl[i][e];
            v += __shfl_xor(v, 1); v += __shfl_xor(v, 2);
            v += __shfl_xor(v, 4); v += __shfl_xor(v, 8);
            if (l15 == 0)
                csum4[w][i * 16 + quad * 4 + e] += v;
        }
    __syncthreads();
    if (t < 128) {
        const int half = t >> 6, local = t & 63;
        const float v = csum4[half][local] + csum4[half + 2][local];
        part[((size_t)ls * NPART + by) * MM + bx * 128 + t] = v * PROB;
    }
}

// ---------------------------------------------------------------------------
// bfin v3: PARALLEL partial reduction. grid = cnt*64 (block = 64 columns),
// 256 threads = 64 cols x 4 p-groups; 4-way LDS merge, gfun on t<64.
// ---------------------------------------------------------------------------
__global__ __launch_bounds__(256) void bfin_kernel(const float* __restrict__ part,
                                                   float* __restrict__ bvec,
                                                   int np4 /* = nparts/4 */)
{
    __shared__ float red[4][64];
    const int t = threadIdx.x;
    const int col = t & 63, pgrp = t >> 6;
    const int ls = blockIdx.x >> 6;
    const int cblk = blockIdx.x & 63;
    const int m = cblk * 64 + col;

    const float* pp = part + (size_t)ls * NPART * MM + (size_t)pgrp * np4 * MM + m;
    float s = 0.f;
#pragma unroll 8
    for (int p = 0; p < np4; ++p) s += pp[(size_t)p * MM];
    red[pgrp][col] = s;
    __syncthreads();
    if (t < 64) {
        const float S = red[0][t] + red[1][t] + red[2][t] + red[3][t];
        bvec[(size_t)ls * MM + cblk * 64 + t] = gfun(S);
    }
}

// ---------------------------------------------------------------------------
// FUSED iteration pass (v9): ONE read of K per Sinkhorn iteration.
// Thread t owns cols [8t,8t+8) and [2048+8t, 2048+8t+8): BOTH loads are
// perfectly coalesced (lane-contiguous 1KB/instruction). Ping-pong prefetch
// kv[2][4][2]: next 4-row batch's loads issue before current batch's dot,
// overlapping HBM latency with dot+shfl+barrier. No atomics anywhere.
// 32 rows/block, grid = cnt*128. One barrier per 4-row batch.
// ---------------------------------------------------------------------------
__global__ __launch_bounds__(256) void fused_kernel(const u16* __restrict__ Ks,
                                                    const float* __restrict__ bvec,
                                                    float* __restrict__ part)
{
    const int t = threadIdx.x, w = t >> 6, lane = t & 63;
    const int ls = blockIdx.x >> 7;
    const int chunk = blockIdx.x & 127;

    __shared__ float wp[2][4][4];  // [parity][row-in-batch][wave]

    // b for this thread's two 8-col runs -> registers
    const float* bp = bvec + (size_t)ls * MM + t * 8;
    float bv[16];
#pragma unroll
    for (int i = 0; i < 2; ++i) {
        f32x4 b0 = *(const f32x4*)(bp + i * 2048);
        f32x4 b1 = *(const f32x4*)(bp + i * 2048 + 4);
        bv[i * 8 + 0] = b0.x; bv[i * 8 + 1] = b0.y;
        bv[i * 8 + 2] = b0.z; bv[i * 8 + 3] = b0.w;
        bv[i * 8 + 4] = b1.x; bv[i * 8 + 5] = b1.y;
        bv[i * 8 + 6] = b1.z; bv[i * 8 + 7] = b1.w;
    }
    float acc[16];
#pragma unroll
    for (int i = 0; i < 16; ++i) acc[i] = 0.f;

    const u16* kbase = Ks + ((size_t)ls * NN + (size_t)chunk * 32) * MM + t * 8;

    s16x8 kv[2][4][2];
    // preload batch 0
#pragma unroll
    for (int r = 0; r < 4; ++r) {
        kv[0][r][0] = *(const s16x8*)(kbase + (size_t)r * MM);
        kv[0][r][1] = *(const s16x8*)(kbase + (size_t)r * MM + 2048);
    }

#pragma unroll
    for (int rb = 0; rb < 8; ++rb) {
        const int cur = rb & 1, nxt = cur ^ 1;

        // prefetch next batch (issues before current dot's waitcnt)
        if (rb < 7) {
            const u16* kp = kbase + (size_t)((rb + 1) * 4) * MM;
#pragma unroll
            for (int r = 0; r < 4; ++r) {
                kv[nxt][r][0] = *(const s16x8*)(kp + (size_t)r * MM);
                kv[nxt][r][1] = *(const s16x8*)(kp + (size_t)r * MM + 2048);
            }
        }

        // phase 1: dot partials for the 4 current rows, reduce
#pragma unroll
        for (int r = 0; r < 4; ++r) {
            const u16* u0 = (const u16*)&kv[cur][r][0];
            const u16* u1 = (const u16*)&kv[cur][r][1];
            float s = 0.f;
#pragma unroll
            for (int i = 0; i < 8; ++i) s += bf2f(u0[i]) * bv[i];
#pragma unroll
            for (int i = 0; i < 8; ++i) s += bf2f(u1[i]) * bv[8 + i];
            for (int o = 32; o > 0; o >>= 1) s += __shfl_xor(s, o);
            if (lane == 0) wp[cur][r][w] = s;
        }
        __syncthreads();

        // every thread computes the 4 row factors (broadcast LDS reads)
        float ar[4];
#pragma unroll
        for (int r = 0; r < 4; ++r) {
            const float S = wp[cur][r][0] + wp[cur][r][1]
                          + wp[cur][r][2] + wp[cur][r][3];
            ar[r] = gfun(S);
        }

        // phase 2: accumulate ar * K from the register-held rows (no loads)
#pragma unroll
        for (int r = 0; r < 4; ++r) {
            const u16* u0 = (const u16*)&kv[cur][r][0];
            const u16* u1 = (const u16*)&kv[cur][r][1];
#pragma unroll
            for (int i = 0; i < 8; ++i) acc[i]     += ar[r] * bf2f(u0[i]);
#pragma unroll
            for (int i = 0; i < 8; ++i) acc[8 + i] += ar[r] * bf2f(u1[i]);
        }
    }

    // flush: plain coalesced stores to this block's private partial slot
    float* kout = part + ((size_t)ls * NPART + chunk) * MM + t * 8;
    *(f32x4*)&kout[0]    = (f32x4){acc[0],  acc[1],  acc[2],  acc[3]};
    *(f32x4*)&kout[4]    = (f32x4){acc[4],  acc[5],  acc[6],  acc[7]};
    *(f32x4*)&kout[2048] = (f32x4){acc[8],  acc[9],  acc[10], acc[11]};
    *(f32x4*)&kout[2052] = (f32x4){acc[12], acc[13], acc[14], acc[15]};
}

// ---------------------------------------------------------------------------
// bp4 PLANAR: bp4[ls][0][m]=b, [1][m]=b*x, [2][m]=b*y, [3][m]=b*z
// ---------------------------------------------------------------------------
__global__ __launch_bounds__(256) void bp4_kernel(const float* __restrict__ bvec,
                                                  const float* __restrict__ p2,
                                                  float* __restrict__ bp4)
{
    const int t = blockIdx.x * 256 + threadIdx.x;   // over cnt*MM
    const int ls = t >> 12;
    const int m = t & 4095;
    const float bv = bvec[t];
    const float x = p2[(size_t)t * 3 + 0];
    const float y = p2[(size_t)t * 3 + 1];
    const float z = p2[(size_t)t * 3 + 2];
    float* pb = bp4 + (size_t)ls * MM * 4;
    pb[m]          = bv;
    pb[MM + m]     = bv * x;
    pb[2 * MM + m] = bv * y;
    pb[3 * MM + m] = bv * z;
}

// ---------------------------------------------------------------------------
// Final pass: planar bp4 staged in LDS (64 KB, loaded once per block),
// 64 rows/block, wave-per-row. s0 = Kb -> a_10 derived here.
// wc4 = { corr_x, corr_y, corr_z, weight }. grid = cnt*64.
// ---------------------------------------------------------------------------
__global__ __launch_bounds__(256) void final_kernel(const u16* __restrict__ Ks,
                                                    const float* __restrict__ bp4,
                                                    float* __restrict__ wc4)
{
    __shared__ float planes[4][4096];   // exactly 64 KB
    const int t = threadIdx.x, w = t >> 6, lane = t & 63;
    const int ls = blockIdx.x >> 6;
    const int chunk = blockIdx.x & 63;

    const float* pb = bp4 + (size_t)ls * MM * 4;
#pragma unroll
    for (int p = 0; p < 4; ++p)
#pragma unroll
        for (int i = 0; i < 4; ++i) {
            const int idx = i * 1024 + t * 4;
            *(f32x4*)&planes[p][idx] = *(const f32x4*)(pb + p * MM + idx);
        }
    __syncthreads();

    for (int rr = 0; rr < 16; ++rr) {
        const int n = chunk * 64 + rr * 4 + w;
        const u16* kp = Ks + ((size_t)ls * NN + n) * MM;
        float s0 = 0.f, s1 = 0.f, s2 = 0.f, s3 = 0.f;
#pragma unroll 4
        for (int pass = 0; pass < 16; ++pass) {
            const int m = pass * 256 + lane * 4;
            u16x4 k4 = *(const u16x4*)(kp + m);
            f32x4 p0 = *(const f32x4*)&planes[0][m];
            f32x4 p1 = *(const f32x4*)&planes[1][m];
            f32x4 p2v = *(const f32x4*)&planes[2][m];
            f32x4 p3 = *(const f32x4*)&planes[3][m];
            const float k0 = bf2f(k4.x), k1 = bf2f(k4.y);
            const float k2 = bf2f(k4.z), k3 = bf2f(k4.w);
            s0 += k0 * p0.x + k1 * p0.y + k2 * p0.z + k3 * p0.w;
            s1 += k0 * p1.x + k1 * p1.y + k2 * p1.z + k3 * p1.w;
            s2 += k0 * p2v.x + k1 * p2v.y + k2 * p2v.z + k3 * p2v.w;
            s3 += k0 * p3.x + k1 * p3.y + k2 * p3.z + k3 * p3.w;
        }
        for (int o = 32; o > 0; o >>= 1) {
            s0 += __shfl_xor(s0, o); s1 += __shfl_xor(s1, o);
            s2 += __shfl_xor(s2, o); s3 += __shfl_xor(s3, o);
        }
        if (lane == 0) {
            const float av = gfun(s0);
            const float wgt = av * s0;
            const float inv = 1.f / (wgt + 1e-8f);
            f32x4 o = {av * s1 * inv, av * s2 * inv, av * s3 * inv, wgt};
            *(f32x4*)&wc4[((size_t)ls * NN + n) * 4] = o;
        }
    }
}

// ---------------------------------------------------------------------------
// Weighted Kabsch per batch: fp64 reduction + one-sided Jacobi SVD (3x3)
// ---------------------------------------------------------------------------
__global__ __launch_bounds__(256) void kabsch_kernel(const float* __restrict__ wc4,
                                                     const float* __restrict__ p1,
                                                     float* __restrict__ out)
{
    const int b = blockIdx.x;
    const int t = threadIdx.x, w = t >> 6, lane = t & 63;
    double acc[16];
#pragma unroll
    for (int k = 0; k < 16; ++k) acc[k] = 0.0;

    for (int n = t; n < NN; n += 256) {
        const float* wp = wc4 + ((size_t)b * NN + n) * 4;
        const float cx = wp[0], cy = wp[1], cz = wp[2], wgt = wp[3];
        const float* pp = p1 + ((size_t)b * NN + n) * 3;
        const double px = pp[0], py = pp[1], pz = pp[2];
        const double wd = wgt;
        const double wcx = wd * cx, wcy = wd * cy, wcz = wd * cz;
        acc[0] += wd;
        acc[1] += wd * px; acc[2] += wd * py; acc[3] += wd * pz;
        acc[4] += wcx;     acc[5] += wcy;     acc[6] += wcz;
        acc[7]  += px * wcx; acc[8]  += px * wcy; acc[9]  += px * wcz;
        acc[10] += py * wcx; acc[11] += py * wcy; acc[12] += py * wcz;
        acc[13] += pz * wcx; acc[14] += pz * wcy; acc[15] += pz * wcz;
    }

    __shared__ double red[4][16];
#pragma unroll
    for (int k = 0; k < 16; ++k) {
        double v = acc[k];
        for (int o = 32; o > 0; o >>= 1) v += __shfl_xor(v, o);
        acc[k] = v;
    }
    if (lane == 0)
        for (int k = 0; k < 16; ++k) red[w][k] = acc[k];
    __syncthreads();

    if (t == 0) {
        double S[16];
        for (int k = 0; k < 16; ++k)
            S[k] = red[0][k] + red[1][k] + red[2][k] + red[3][k];
        const double denom = S[0] + 1e-5;
        const double sfrac = S[0] / denom;
        double ca[3] = {S[1] / denom, S[2] / denom, S[3] / denom};
        double cb[3] = {S[4] / denom, S[5] / denom, S[6] / denom};
        double A[3][3], V[3][3];
        for (int i = 0; i < 3; ++i)
            for (int j = 0; j < 3; ++j) {
                A[i][j] = S[7 + i * 3 + j] / denom - (2.0 - sfrac) * ca[i] * cb[j];
                V[i][j] = (i == j) ? 1.0 : 0.0;
            }
        for (int sweep = 0; sweep < 20; ++sweep) {
            const int PP[3] = {0, 0, 1}, QQ[3] = {1, 2, 2};
            for (int r = 0; r < 3; ++r) {
                const int p = PP[r], q = QQ[r];
                double app = 0, aqq = 0, apq = 0;
                for (int i = 0; i < 3; ++i) {
                    app += A[i][p] * A[i][p];
                    aqq += A[i][q] * A[i][q];
                    apq += A[i][p] * A[i][q];
                }
                if (fabs(apq) < 1e-14 * (app + aqq) + 1e-300) continue;
                const double th = 0.5 * atan2(2.0 * apq, app - aqq);
                const double c = cos(th), sn = sin(th);
                for (int i = 0; i < 3; ++i) {
                    double x = A[i][p], y = A[i][q];
                    A[i][p] = c * x + sn * y; A[i][q] = -sn * x + c * y;
                    x = V[i][p]; y = V[i][q];
                    V[i][p] = c * x + sn * y; V[i][q] = -sn * x + c * y;
                }
            }
        }
        double sv[3];
        for (int j = 0; j < 3; ++j)
            sv[j] = sqrt(A[0][j] * A[0][j] + A[1][j] * A[1][j] + A[2][j] * A[2][j]);
        int idx[3] = {0, 1, 2};
        if (sv[idx[0]] < sv[idx[1]]) { int x = idx[0]; idx[0] = idx[1]; idx[1] = x; }
        if (sv[idx[0]] < sv[idx[2]]) { int x = idx[0]; idx[0] = idx[2]; idx[2] = x; }
        if (sv[idx[1]] < sv[idx[2]]) { int x = idx[1]; idx[1] = idx[2]; idx[2] = x; }
        double U[3][3], Vs[3][3];
        for (int j = 0; j < 3; ++j) {
            const int jj = idx[j];
            const double inv = 1.0 / fmax(sv[jj], 1e-300);
            for (int i = 0; i < 3; ++i) {
                U[i][j] = A[i][jj] * inv;
                Vs[i][j] = V[i][jj];
            }
        }
        double R[3][3];
        for (int i = 0; i < 3; ++i)
            for (int j = 0; j < 3; ++j)
                R[i][j] = Vs[i][0] * U[j][0] + Vs[i][1] * U[j][1] + Vs[i][2] * U[j][2];
        const double det = R[0][0] * (R[1][1] * R[2][2] - R[1][2] * R[2][1])
                         - R[0][1] * (R[1][0] * R[2][2] - R[1][2] * R[2][0])
                         + R[0][2] * (R[1][0] * R[2][1] - R[1][1] * R[2][0]);
        if (det < 0.0) {
            for (int i = 0; i < 3; ++i) Vs[i][2] = -Vs[i][2];
            for (int i = 0; i < 3; ++i)
                for (int j = 0; j < 3; ++j)
                    R[i][j] = Vs[i][0] * U[j][0] + Vs[i][1] * U[j][1] + Vs[i][2] * U[j][2];
        }
        double tr[3];
        for (int i = 0; i < 3; ++i)
            tr[i] = cb[i] - (R[i][0] * ca[0] + R[i][1] * ca[1] + R[i][2] * ca[2]);
        float* o = out + b * 12;
        for (int i = 0; i < 3; ++i) {
            o[i * 4 + 0] = (float)R[i][0];
            o[i * 4 + 1] = (float)R[i][1];
            o[i * 4 + 2] = (float)R[i][2];
            o[i * 4 + 3] = (float)tr[i];
        }
    }
}

// ---------------------------------------------------------------------------
extern "C" void kernel_launch(void* const* d_in, const int* in_sizes, int n_in,
                              void* d_out, int out_size, void* d_ws, size_t ws_size,
                              hipStream_t stream) {
    const float* f1 = (const float*)d_in[0];
    const float* f2 = (const float*)d_in[1];
    const float* p1 = (const float*)d_in[2];
    const float* p2 = (const float*)d_in[3];
    float* out = (float*)d_out;

    const size_t AL = 256;
    const size_t szK    = (size_t)NN * MM * 2;
    const size_t szF1   = (size_t)NN * CC * 2;
    const size_t szF2   = (size_t)MM * CC * 2;
    const size_t szB    = (size_t)MM * 4;
    const size_t szPart = (size_t)NPART * MM * 4;   // 2 MB
    const size_t szBp4  = (size_t)MM * 16;
    const size_t szWc4  = (size_t)NN * 16;
    const size_t per_batch = szK + szF1 + szF2 + szB + szPart + szBp4 + szWc4 + 8 * AL;

    int NS = (int)(ws_size / per_batch);
    if (NS > NB) NS = NB;
    if (NS < 1) NS = 1;

    char* base = (char*)d_ws;
    size_t off = 0;
    auto carve = [&](size_t bytes) -> char* {
        char* p = base + off;
        off += (bytes + AL - 1) & ~(AL - 1);
        return p;
    };
    u16*   Ks   = (u16*)  carve((size_t)NS * szK);
    u16*   f1s  = (u16*)  carve((size_t)NS * szF1);
    u16*   f2s  = (u16*)  carve((size_t)NS * szF2);
    float* bvec = (float*)carve((size_t)NS * szB);
    float* part = (float*)carve((size_t)NS * szPart);
    float* bp4  = (float*)carve((size_t)NS * szBp4);
    float* wc4  = (float*)carve((size_t)NS * szWc4);

    for (int b0 = 0; b0 < NB; b0 += NS) {
        const int cnt = (NB - b0 < NS) ? (NB - b0) : NS;

        norm_kernel<<<cnt * NN / 4, 256, 0, stream>>>(f1 + (size_t)b0 * NN * CC, f1s);
        norm_kernel<<<cnt * MM / 4, 256, 0, stream>>>(f2 + (size_t)b0 * MM * CC, f2s);
        // GEMM writes K and iteration-1 colsum partials (slots 0..31)
        gemm_exp_kernel<<<dim3(MM / 128, NN / 128, cnt), 256, 0, stream>>>(f1s, f2s, Ks, part);
        bfin_kernel<<<cnt * 64, 256, 0, stream>>>(part, bvec, 8);    // 32 partials

        for (int it = 0; it < 9; ++it) {
            fused_kernel<<<cnt * 128, 256, 0, stream>>>(Ks, bvec, part);
            bfin_kernel<<<cnt * 64, 256, 0, stream>>>(part, bvec, 32);   // 128 partials
        }

        bp4_kernel<<<cnt * MM / 256, 256, 0, stream>>>(bvec, p2 + (size_t)b0 * MM * 3, bp4);
        final_kernel<<<cnt * 64, 256, 0, stream>>>(Ks, bp4, wc4);
        kabsch_kernel<<<cnt, 256, 0, stream>>>(wc4, p1 + (size_t)b0 * NN * 3, out + (size_t)b0 * 12);
    }

    (void)in_sizes; (void)n_in; (void)out_size;
}

// Round 12
// 934.567 us; speedup vs baseline: 2.1798x; 2.1798x over previous
//
#include <hip/hip_runtime.h>

#define NB 8
#define NN 4096
#define MM 4096
#define CC 256
#define NPART 128   /* fused partial slots per batch */

typedef unsigned short u16;
typedef __attribute__((ext_vector_type(4))) unsigned short u16x4;
typedef __attribute__((ext_vector_type(8))) short s16x8;
typedef __attribute__((ext_vector_type(4))) float f32x4;

#define INV_EPS 33.333333333333336f
#define EXP2_SCALE 48.089834696296504f   /* INV_EPS / ln(2) */
#define POWER   0.94339622641509435f     /* 0.5/(0.5+0.03) */
#define PROB    (1.0f/4096.0f)

static __device__ __forceinline__ float bf2f(u16 h) {
    union { unsigned int u; float f; } v;
    v.u = ((unsigned int)h) << 16;
    return v.f;
}
static __device__ __forceinline__ u16 f2bf(float f) {
    union { float f; unsigned int u; } v;
    v.f = f;
    unsigned int u = v.u;
    u += 0x7fffu + ((u >> 16) & 1u);   // round-to-nearest-even
    return (u16)(u >> 16);
}
static __device__ __forceinline__ float gfun(float x) {
    // (PROB / (x + 1e-8))^POWER, x > 0
    return exp2f(POWER * log2f(PROB / (x + 1e-8f)));
}

// ---------------------------------------------------------------------------
// L2-normalize rows of (rows x 256) fp32 -> bf16. One wave per row.
// ---------------------------------------------------------------------------
__global__ __launch_bounds__(256) void norm_kernel(const float* __restrict__ src,
                                                   u16* __restrict__ dst)
{
    const int t = threadIdx.x, w = t >> 6, lane = t & 63;
    const size_t row = (size_t)blockIdx.x * 4 + w;
    const float* sp = src + row * CC + lane * 4;
    f32x4 v = *(const f32x4*)sp;
    float s = v.x * v.x + v.y * v.y + v.z * v.z + v.w * v.w;
    for (int o = 32; o > 0; o >>= 1) s += __shfl_xor(s, o);
    float rn = rsqrtf(s + 1e-8f);
    u16x4 o4;
    o4.x = f2bf(v.x * rn); o4.y = f2bf(v.y * rn);
    o4.z = f2bf(v.z * rn); o4.w = f2bf(v.w * rn);
    *(u16x4*)(dst + row * CC + lane * 4) = o4;
}

// ---------------------------------------------------------------------------
// Strip GEMM: Ks[ls][r][c] = exp((f1s[ls][r]·f2s[ls][c] - 1)/eps), bf16 out.
// Epilogue writes iteration-1 colsum partial (slot = by, plain stores, no
// atomics). LDSS=68: fragment-read bank = 2*l15+4*quad mod 32 -> <=2-way.
// ---------------------------------------------------------------------------
#define LDSS 68   /* 64 + 4 pad, in u16 units: conflict-free MFMA reads */

__global__ __launch_bounds__(256, 3) void gemm_exp_kernel(
    const u16* __restrict__ f1s, const u16* __restrict__ f2s,
    u16* __restrict__ Ks, float* __restrict__ part)
{
    const int t = threadIdx.x;
    const int w = t >> 6, lane = t & 63;
    const int quad = lane >> 4, l15 = lane & 15;
    const int bx = blockIdx.x;   // c-tile (f2 rows)
    const int by = blockIdx.y;   // r-tile (f1 rows)
    const int ls = blockIdx.z;   // local batch in strip

    __shared__ u16 As[128 * LDSS];
    __shared__ u16 Bs[128 * LDSS];
    __shared__ float csum4[4][64];   // per-wave colsum partials (no atomics)

    csum4[w][lane] = 0.f;   // covered by first loop's __syncthreads

    const u16* f2base = f2s + ((size_t)ls * MM + (size_t)bx * 128) * CC;
    const u16* f1base = f1s + ((size_t)ls * NN + (size_t)by * 128) * CC;

    f32x4 acc[4][4];
#pragma unroll
    for (int i = 0; i < 4; ++i)
#pragma unroll
        for (int j = 0; j < 4; ++j) acc[i][j] = (f32x4){0.f, 0.f, 0.f, 0.f};

    const int g_r = t >> 3;
    const int g_c = (t & 7) << 3;

    for (int kt = 0; kt < 4; ++kt) {
        const int k0 = kt * 64;
        __syncthreads();
#pragma unroll
        for (int i = 0; i < 4; ++i) {
            const int row = g_r + i * 32;
            s16x8 va = *(const s16x8*)(f2base + (size_t)row * CC + k0 + g_c);
            s16x8 vb = *(const s16x8*)(f1base + (size_t)row * CC + k0 + g_c);
            *(s16x8*)&As[row * LDSS + g_c] = va;
            *(s16x8*)&Bs[row * LDSS + g_c] = vb;
        }
        __syncthreads();
#pragma unroll
        for (int s = 0; s < 2; ++s) {
            s16x8 af[4], bfr[4];
#pragma unroll
            for (int i = 0; i < 4; ++i)
                af[i] = *(const s16x8*)&As[((w & 1) * 64 + i * 16 + l15) * LDSS + s * 32 + quad * 8];
#pragma unroll
            for (int j = 0; j < 4; ++j)
                bfr[j] = *(const s16x8*)&Bs[((w >> 1) * 64 + j * 16 + l15) * LDSS + s * 32 + quad * 8];
#pragma unroll
            for (int i = 0; i < 4; ++i)
#pragma unroll
                for (int j = 0; j < 4; ++j)
                    acc[i][j] = __builtin_amdgcn_mfma_f32_16x16x32_bf16(af[i], bfr[j], acc[i][j], 0, 0, 0);
        }
    }

    u16* kb = Ks + (size_t)ls * NN * MM;
    const int rbase = by * 128 + (w >> 1) * 64 + l15;
    const int cbase = bx * 128 + (w & 1) * 64 + quad * 4;
    float partl[4][4];
#pragma unroll
    for (int i = 0; i < 4; ++i)
#pragma unroll
        for (int e = 0; e < 4; ++e) partl[i][e] = 0.f;

#pragma unroll
    for (int j = 0; j < 4; ++j) {
        const int r = rbase + j * 16;
#pragma unroll
        for (int i = 0; i < 4; ++i) {
            const int c = cbase + i * 16;
            f32x4 v = acc[i][j];
            const float e0 = exp2f((v.x - 1.f) * EXP2_SCALE);
            const float e1 = exp2f((v.y - 1.f) * EXP2_SCALE);
            const float e2 = exp2f((v.z - 1.f) * EXP2_SCALE);
            const float e3 = exp2f((v.w - 1.f) * EXP2_SCALE);
            u16x4 o;
            o.x = f2bf(e0); o.y = f2bf(e1); o.z = f2bf(e2); o.w = f2bf(e3);
            *(u16x4*)&kb[(size_t)r * MM + c] = o;
            partl[i][0] += e0; partl[i][1] += e1; partl[i][2] += e2; partl[i][3] += e3;
        }
    }

    // reduce colsums over the 16 l15 lanes of each quad; plain += into the
    // wave-private region (active lanes hit distinct addresses -> no race)
#pragma unroll
    for (int i = 0; i < 4; ++i)
#pragma unroll
        for (int e = 0; e < 4; ++e) {
            float v = partl[i][e];
            v += __shfl_xor(v, 1); v += __shfl_xor(v, 2);
            v += __shfl_xor(v, 4); v += __shfl_xor(v, 8);
            if (l15 == 0)
                csum4[w][i * 16 + quad * 4 + e] += v;
        }
    __syncthreads();
    if (t < 128) {
        const int half = t >> 6, local = t & 63;
        const float v = csum4[half][local] + csum4[half + 2][local];
        part[((size_t)ls * NPART + by) * MM + bx * 128 + t] = v * PROB;
    }
}

// ---------------------------------------------------------------------------
// bfin v3: PARALLEL partial reduction. grid = cnt*64 (block = 64 columns),
// 256 threads = 64 cols x 4 p-groups; 4-way LDS merge, gfun on t<64.
// ---------------------------------------------------------------------------
__global__ __launch_bounds__(256) void bfin_kernel(const float* __restrict__ part,
                                                   float* __restrict__ bvec,
                                                   int np4 /* = nparts/4 */)
{
    __shared__ float red[4][64];
    const int t = threadIdx.x;
    const int col = t & 63, pgrp = t >> 6;
    const int ls = blockIdx.x >> 6;
    const int cblk = blockIdx.x & 63;
    const int m = cblk * 64 + col;

    const float* pp = part + (size_t)ls * NPART * MM + (size_t)pgrp * np4 * MM + m;
    float s = 0.f;
#pragma unroll 8
    for (int p = 0; p < np4; ++p) s += pp[(size_t)p * MM];
    red[pgrp][col] = s;
    __syncthreads();
    if (t < 64) {
        const float S = red[0][t] + red[1][t] + red[2][t] + red[3][t];
        bvec[(size_t)ls * MM + cblk * 64 + t] = gfun(S);
    }
}

// ---------------------------------------------------------------------------
// FUSED iteration pass (v10): v8 structure (NO prefetch - R11 proved the
// doubled kv buffer spills at 256 VGPR) + dense coalescing: thread t owns
// cols [8t,8t+8) and [2048+8t,2048+8t+8) -> both 16B/lane loads are
// lane-contiguous 1KB/instruction. kv[4][2]=32 VGPRs, live ~80. No atomics.
// 32 rows/block, grid = cnt*128. One barrier per 4-row batch.
// ---------------------------------------------------------------------------
__global__ __launch_bounds__(256) void fused_kernel(const u16* __restrict__ Ks,
                                                    const float* __restrict__ bvec,
                                                    float* __restrict__ part)
{
    const int t = threadIdx.x, w = t >> 6, lane = t & 63;
    const int ls = blockIdx.x >> 7;
    const int chunk = blockIdx.x & 127;

    __shared__ float wp[2][4][4];  // [parity][row-in-batch][wave]

    // b for this thread's two 8-col runs -> registers
    const float* bp = bvec + (size_t)ls * MM + t * 8;
    float bv[16];
#pragma unroll
    for (int i = 0; i < 2; ++i) {
        f32x4 b0 = *(const f32x4*)(bp + i * 2048);
        f32x4 b1 = *(const f32x4*)(bp + i * 2048 + 4);
        bv[i * 8 + 0] = b0.x; bv[i * 8 + 1] = b0.y;
        bv[i * 8 + 2] = b0.z; bv[i * 8 + 3] = b0.w;
        bv[i * 8 + 4] = b1.x; bv[i * 8 + 5] = b1.y;
        bv[i * 8 + 6] = b1.z; bv[i * 8 + 7] = b1.w;
    }
    float acc[16];
#pragma unroll
    for (int i = 0; i < 16; ++i) acc[i] = 0.f;

    const u16* kbase = Ks + ((size_t)ls * NN + (size_t)chunk * 32) * MM + t * 8;

    for (int rb = 0; rb < 8; ++rb) {
        const u16* kp = kbase + (size_t)(rb * 4) * MM;
        const int par = rb & 1;

        // phase 1: load 4 rows (kept packed in regs), dot partials, reduce
        s16x8 kv[4][2];
#pragma unroll
        for (int r = 0; r < 4; ++r) {
            kv[r][0] = *(const s16x8*)(kp + (size_t)r * MM);
            kv[r][1] = *(const s16x8*)(kp + (size_t)r * MM + 2048);
        }
#pragma unroll
        for (int r = 0; r < 4; ++r) {
            const u16* u0 = (const u16*)&kv[r][0];
            const u16* u1 = (const u16*)&kv[r][1];
            float s = 0.f;
#pragma unroll
            for (int i = 0; i < 8; ++i) s += bf2f(u0[i]) * bv[i];
#pragma unroll
            for (int i = 0; i < 8; ++i) s += bf2f(u1[i]) * bv[8 + i];
            for (int o = 32; o > 0; o >>= 1) s += __shfl_xor(s, o);
            if (lane == 0) wp[par][r][w] = s;
        }
        __syncthreads();

        // every thread computes the 4 row factors (broadcast LDS reads)
        float ar[4];
#pragma unroll
        for (int r = 0; r < 4; ++r) {
            const float S = wp[par][r][0] + wp[par][r][1]
                          + wp[par][r][2] + wp[par][r][3];
            ar[r] = gfun(S);
        }

        // phase 2: accumulate ar * K from the register-held rows (no loads)
#pragma unroll
        for (int r = 0; r < 4; ++r) {
            const u16* u0 = (const u16*)&kv[r][0];
            const u16* u1 = (const u16*)&kv[r][1];
#pragma unroll
            for (int i = 0; i < 8; ++i) acc[i]     += ar[r] * bf2f(u0[i]);
#pragma unroll
            for (int i = 0; i < 8; ++i) acc[8 + i] += ar[r] * bf2f(u1[i]);
        }
    }

    // flush: plain coalesced stores to this block's private partial slot
    float* kout = part + ((size_t)ls * NPART + chunk) * MM + t * 8;
    *(f32x4*)&kout[0]    = (f32x4){acc[0],  acc[1],  acc[2],  acc[3]};
    *(f32x4*)&kout[4]    = (f32x4){acc[4],  acc[5],  acc[6],  acc[7]};
    *(f32x4*)&kout[2048] = (f32x4){acc[8],  acc[9],  acc[10], acc[11]};
    *(f32x4*)&kout[2052] = (f32x4){acc[12], acc[13], acc[14], acc[15]};
}

// ---------------------------------------------------------------------------
// bp4 PLANAR: bp4[ls][0][m]=b, [1][m]=b*x, [2][m]=b*y, [3][m]=b*z
// ---------------------------------------------------------------------------
__global__ __launch_bounds__(256) void bp4_kernel(const float* __restrict__ bvec,
                                                  const float* __restrict__ p2,
                                                  float* __restrict__ bp4)
{
    const int t = blockIdx.x * 256 + threadIdx.x;   // over cnt*MM
    const int ls = t >> 12;
    const int m = t & 4095;
    const float bv = bvec[t];
    const float x = p2[(size_t)t * 3 + 0];
    const float y = p2[(size_t)t * 3 + 1];
    const float z = p2[(size_t)t * 3 + 2];
    float* pb = bp4 + (size_t)ls * MM * 4;
    pb[m]          = bv;
    pb[MM + m]     = bv * x;
    pb[2 * MM + m] = bv * y;
    pb[3 * MM + m] = bv * z;
}

// ---------------------------------------------------------------------------
// Final pass: planar bp4 staged in LDS (64 KB, loaded once per block),
// 64 rows/block, wave-per-row. s0 = Kb -> a_10 derived here.
// wc4 = { corr_x, corr_y, corr_z, weight }. grid = cnt*64.
// ---------------------------------------------------------------------------
__global__ __launch_bounds__(256) void final_kernel(const u16* __restrict__ Ks,
                                                    const float* __restrict__ bp4,
                                                    float* __restrict__ wc4)
{
    __shared__ float planes[4][4096];   // exactly 64 KB
    const int t = threadIdx.x, w = t >> 6, lane = t & 63;
    const int ls = blockIdx.x >> 6;
    const int chunk = blockIdx.x & 63;

    const float* pb = bp4 + (size_t)ls * MM * 4;
#pragma unroll
    for (int p = 0; p < 4; ++p)
#pragma unroll
        for (int i = 0; i < 4; ++i) {
            const int idx = i * 1024 + t * 4;
            *(f32x4*)&planes[p][idx] = *(const f32x4*)(pb + p * MM + idx);
        }
    __syncthreads();

    for (int rr = 0; rr < 16; ++rr) {
        const int n = chunk * 64 + rr * 4 + w;
        const u16* kp = Ks + ((size_t)ls * NN + n) * MM;
        float s0 = 0.f, s1 = 0.f, s2 = 0.f, s3 = 0.f;
#pragma unroll 4
        for (int pass = 0; pass < 16; ++pass) {
            const int m = pass * 256 + lane * 4;
            u16x4 k4 = *(const u16x4*)(kp + m);
            f32x4 p0 = *(const f32x4*)&planes[0][m];
            f32x4 p1 = *(const f32x4*)&planes[1][m];
            f32x4 p2v = *(const f32x4*)&planes[2][m];
            f32x4 p3 = *(const f32x4*)&planes[3][m];
            const float k0 = bf2f(k4.x), k1 = bf2f(k4.y);
            const float k2 = bf2f(k4.z), k3 = bf2f(k4.w);
            s0 += k0 * p0.x + k1 * p0.y + k2 * p0.z + k3 * p0.w;
            s1 += k0 * p1.x + k1 * p1.y + k2 * p1.z + k3 * p1.w;
            s2 += k0 * p2v.x + k1 * p2v.y + k2 * p2v.z + k3 * p2v.w;
            s3 += k0 * p3.x + k1 * p3.y + k2 * p3.z + k3 * p3.w;
        }
        for (int o = 32; o > 0; o >>= 1) {
            s0 += __shfl_xor(s0, o); s1 += __shfl_xor(s1, o);
            s2 += __shfl_xor(s2, o); s3 += __shfl_xor(s3, o);
        }
        if (lane == 0) {
            const float av = gfun(s0);
            const float wgt = av * s0;
            const float inv = 1.f / (wgt + 1e-8f);
            f32x4 o = {av * s1 * inv, av * s2 * inv, av * s3 * inv, wgt};
            *(f32x4*)&wc4[((size_t)ls * NN + n) * 4] = o;
        }
    }
}

// ---------------------------------------------------------------------------
// Weighted Kabsch per batch: fp64 reduction + one-sided Jacobi SVD (3x3)
// ---------------------------------------------------------------------------
__global__ __launch_bounds__(256) void kabsch_kernel(const float* __restrict__ wc4,
                                                     const float* __restrict__ p1,
                                                     float* __restrict__ out)
{
    const int b = blockIdx.x;
    const int t = threadIdx.x, w = t >> 6, lane = t & 63;
    double acc[16];
#pragma unroll
    for (int k = 0; k < 16; ++k) acc[k] = 0.0;

    for (int n = t; n < NN; n += 256) {
        const float* wp = wc4 + ((size_t)b * NN + n) * 4;
        const float cx = wp[0], cy = wp[1], cz = wp[2], wgt = wp[3];
        const float* pp = p1 + ((size_t)b * NN + n) * 3;
        const double px = pp[0], py = pp[1], pz = pp[2];
        const double wd = wgt;
        const double wcx = wd * cx, wcy = wd * cy, wcz = wd * cz;
        acc[0] += wd;
        acc[1] += wd * px; acc[2] += wd * py; acc[3] += wd * pz;
        acc[4] += wcx;     acc[5] += wcy;     acc[6] += wcz;
        acc[7]  += px * wcx; acc[8]  += px * wcy; acc[9]  += px * wcz;
        acc[10] += py * wcx; acc[11] += py * wcy; acc[12] += py * wcz;
        acc[13] += pz * wcx; acc[14] += pz * wcy; acc[15] += pz * wcz;
    }

    __shared__ double red[4][16];
#pragma unroll
    for (int k = 0; k < 16; ++k) {
        double v = acc[k];
        for (int o = 32; o > 0; o >>= 1) v += __shfl_xor(v, o);
        acc[k] = v;
    }
    if (lane == 0)
        for (int k = 0; k < 16; ++k) red[w][k] = acc[k];
    __syncthreads();

    if (t == 0) {
        double S[16];
        for (int k = 0; k < 16; ++k)
            S[k] = red[0][k] + red[1][k] + red[2][k] + red[3][k];
        const double denom = S[0] + 1e-5;
        const double sfrac = S[0] / denom;
        double ca[3] = {S[1] / denom, S[2] / denom, S[3] / denom};
        double cb[3] = {S[4] / denom, S[5] / denom, S[6] / denom};
        double A[3][3], V[3][3];
        for (int i = 0; i < 3; ++i)
            for (int j = 0; j < 3; ++j) {
                A[i][j] = S[7 + i * 3 + j] / denom - (2.0 - sfrac) * ca[i] * cb[j];
                V[i][j] = (i == j) ? 1.0 : 0.0;
            }
        for (int sweep = 0; sweep < 20; ++sweep) {
            const int PP[3] = {0, 0, 1}, QQ[3] = {1, 2, 2};
            for (int r = 0; r < 3; ++r) {
                const int p = PP[r], q = QQ[r];
                double app = 0, aqq = 0, apq = 0;
                for (int i = 0; i < 3; ++i) {
                    app += A[i][p] * A[i][p];
                    aqq += A[i][q] * A[i][q];
                    apq += A[i][p] * A[i][q];
                }
                if (fabs(apq) < 1e-14 * (app + aqq) + 1e-300) continue;
                const double th = 0.5 * atan2(2.0 * apq, app - aqq);
                const double c = cos(th), sn = sin(th);
                for (int i = 0; i < 3; ++i) {
                    double x = A[i][p], y = A[i][q];
                    A[i][p] = c * x + sn * y; A[i][q] = -sn * x + c * y;
                    x = V[i][p]; y = V[i][q];
                    V[i][p] = c * x + sn * y; V[i][q] = -sn * x + c * y;
                }
            }
        }
        double sv[3];
        for (int j = 0; j < 3; ++j)
            sv[j] = sqrt(A[0][j] * A[0][j] + A[1][j] * A[1][j] + A[2][j] * A[2][j]);
        int idx[3] = {0, 1, 2};
        if (sv[idx[0]] < sv[idx[1]]) { int x = idx[0]; idx[0] = idx[1]; idx[1] = x; }
        if (sv[idx[0]] < sv[idx[2]]) { int x = idx[0]; idx[0] = idx[2]; idx[2] = x; }
        if (sv[idx[1]] < sv[idx[2]]) { int x = idx[1]; idx[1] = idx[2]; idx[2] = x; }
        double U[3][3], Vs[3][3];
        for (int j = 0; j < 3; ++j) {
            const int jj = idx[j];
            const double inv = 1.0 / fmax(sv[jj], 1e-300);
            for (int i = 0; i < 3; ++i) {
                U[i][j] = A[i][jj] * inv;
                Vs[i][j] = V[i][jj];
            }
        }
        double R[3][3];
        for (int i = 0; i < 3; ++i)
            for (int j = 0; j < 3; ++j)
                R[i][j] = Vs[i][0] * U[j][0] + Vs[i][1] * U[j][1] + Vs[i][2] * U[j][2];
        const double det = R[0][0] * (R[1][1] * R[2][2] - R[1][2] * R[2][1])
                         - R[0][1] * (R[1][0] * R[2][2] - R[1][2] * R[2][0])
                         + R[0][2] * (R[1][0] * R[2][1] - R[1][1] * R[2][0]);
        if (det < 0.0) {
            for (int i = 0; i < 3; ++i) Vs[i][2] = -Vs[i][2];
            for (int i = 0; i < 3; ++i)
                for (int j = 0; j < 3; ++j)
                    R[i][j] = Vs[i][0] * U[j][0] + Vs[i][1] * U[j][1] + Vs[i][2] * U[j][2];
        }
        double tr[3];
        for (int i = 0; i < 3; ++i)
            tr[i] = cb[i] - (R[i][0] * ca[0] + R[i][1] * ca[1] + R[i][2] * ca[2]);
        float* o = out + b * 12;
        for (int i = 0; i < 3; ++i) {
            o[i * 4 + 0] = (float)R[i][0];
            o[i * 4 + 1] = (float)R[i][1];
            o[i * 4 + 2] = (float)R[i][2];
            o[i * 4 + 3] = (float)tr[i];
        }
    }
}

// ---------------------------------------------------------------------------
extern "C" void kernel_launch(void* const* d_in, const int* in_sizes, int n_in,
                              void* d_out, int out_size, void* d_ws, size_t ws_size,
                              hipStream_t stream) {
    const float* f1 = (const float*)d_in[0];
    const float* f2 = (const float*)d_in[1];
    const float* p1 = (const float*)d_in[2];
    const float* p2 = (const float*)d_in[3];
    float* out = (float*)d_out;

    const size_t AL = 256;
    const size_t szK    = (size_t)NN * MM * 2;
    const size_t szF1   = (size_t)NN * CC * 2;
    const size_t szF2   = (size_t)MM * CC * 2;
    const size_t szB    = (size_t)MM * 4;
    const size_t szPart = (size_t)NPART * MM * 4;   // 2 MB
    const size_t szBp4  = (size_t)MM * 16;
    const size_t szWc4  = (size_t)NN * 16;
    const size_t per_batch = szK + szF1 + szF2 + szB + szPart + szBp4 + szWc4 + 8 * AL;

    int NS = (int)(ws_size / per_batch);
    if (NS > NB) NS = NB;
    if (NS < 1) NS = 1;

    char* base = (char*)d_ws;
    size_t off = 0;
    auto carve = [&](size_t bytes) -> char* {
        char* p = base + off;
        off += (bytes + AL - 1) & ~(AL - 1);
        return p;
    };
    u16*   Ks   = (u16*)  carve((size_t)NS * szK);
    u16*   f1s  = (u16*)  carve((size_t)NS * szF1);
    u16*   f2s  = (u16*)  carve((size_t)NS * szF2);
    float* bvec = (float*)carve((size_t)NS * szB);
    float* part = (float*)carve((size_t)NS * szPart);
    float* bp4  = (float*)carve((size_t)NS * szBp4);
    float* wc4  = (float*)carve((size_t)NS * szWc4);

    for (int b0 = 0; b0 < NB; b0 += NS) {
        const int cnt = (NB - b0 < NS) ? (NB - b0) : NS;

        norm_kernel<<<cnt * NN / 4, 256, 0, stream>>>(f1 + (size_t)b0 * NN * CC, f1s);
        norm_kernel<<<cnt * MM / 4, 256, 0, stream>>>(f2 + (size_t)b0 * MM * CC, f2s);
        // GEMM writes K and iteration-1 colsum partials (slots 0..31)
        gemm_exp_kernel<<<dim3(MM / 128, NN / 128, cnt), 256, 0, stream>>>(f1s, f2s, Ks, part);
        bfin_kernel<<<cnt * 64, 256, 0, stream>>>(part, bvec, 8);    // 32 partials

        for (int it = 0; it < 9; ++it) {
            fused_kernel<<<cnt * 128, 256, 0, stream>>>(Ks, bvec, part);
            bfin_kernel<<<cnt * 64, 256, 0, stream>>>(part, bvec, 32);   // 128 partials
        }

        bp4_kernel<<<cnt * MM / 256, 256, 0, stream>>>(bvec, p2 + (size_t)b0 * MM * 3, bp4);
        final_kernel<<<cnt * 64, 256, 0, stream>>>(Ks, bp4, wc4);
        kabsch_kernel<<<cnt, 256, 0, stream>>>(wc4, p1 + (size_t)b0 * NN * 3, out + (size_t)b0 * 12);
    }

    (void)in_sizes; (void)n_in; (void)out_size;
}